// Round 12
// baseline (25.405 us; speedup 1.0000x reference)
//
#include <hip/hip_runtime.h>
#include <float.h>
#include <math.h>

// Problem constants (from reference)
constexpr int B  = 16;
constexpr int VS = 10475;
constexpr int VO = 8192;
constexpr int K  = 64;
constexpr int PS = 1024;
constexpr int PO = 2048;

// R12: 3-node structure.
//  node1 cl_gather : ALL scattered (index) reads, 768 blocks (high TLP),
//                    writes dense og[K][PO] / qg[K][PS] float4.
//  node2 cl_onepass: R6 geometry + hot loop BYTE-IDENTICAL; staging is now
//                    coalesced float4 -> LDS (no random addresses at 1 blk/CU).
//  node3 cl_final  : one-wave 256->1 reduce.
constexpr int BLK  = 256;
constexpr int QPB  = 256;              // queries per block
constexpr int GRID = K * (PS / QPB);   // 256
constexpr int NG   = 8;                // jgroups (half-waves) per block
constexpr int JPG  = PO / NG;          // 256 objects per jgroup
constexpr int QL   = 8;                // queries per lane (4 packed pairs)

constexpr int OG_BLOCKS = (K * PO) / 256;   // 512
constexpr int QG_BLOCKS = (K * PS) / 256;   // 256
constexpr int PREP_GRID = OG_BLOCKS + QG_BLOCKS;  // 768

typedef float v2f __attribute__((ext_vector_type(2)));
typedef float v4f __attribute__((ext_vector_type(4)));

// ---------------- node 1: scatter-gather with high TLP ----------------

__global__ __launch_bounds__(256)
void cl_gather(const float* __restrict__ smplx_v,
               const float* __restrict__ object_v,
               const int*   __restrict__ spi,
               const int*   __restrict__ opi,
               const int*   __restrict__ bidx,
               float4*      __restrict__ og,    // [K][PO] (x,y,z, 0.5|o|^2)
               float4*      __restrict__ qg)    // [K][PS] (x,y,z, |s|^2)
{
    const int bid = blockIdx.x;
    const int tid = threadIdx.x;
    if (bid < OG_BLOCKS) {
        const int gid = bid * 256 + tid;        // over K*PO
        const int k   = gid >> 11;              // /PO
        const int b   = bidx[k];
        const int oj  = opi[gid];
        const float* __restrict__ p = object_v + ((size_t)b * VO + oj) * 3;
        const float x = p[0], y = p[1], z = p[2];
        og[gid] = make_float4(x, y, z, 0.5f * (x * x + y * y + z * z));
    } else {
        const int gid = (bid - OG_BLOCKS) * 256 + tid;   // over K*PS
        const int k   = gid >> 10;              // /PS
        const int b   = bidx[k];
        const int si  = spi[gid];
        const float* __restrict__ p = smplx_v + ((size_t)b * VS + si) * 3;
        const float x = p[0], y = p[1], z = p[2];
        qg[gid] = make_float4(x, y, z, x * x + y * y + z * z);
    }
}

// ---------------- node 2: full min + block partial sum ----------------

__global__ __launch_bounds__(BLK)
void cl_onepass(const float4* __restrict__ og,
                const float4* __restrict__ qg,
                float*        __restrict__ partial)   // [GRID]
{
    __shared__ v4f    so[PO];        // 32 KiB
    __shared__ float4 qld[QPB];      //  4 KiB
    __shared__ float  red[NG][QPB];  //  8 KiB
    __shared__ float  rsum[BLK];     //  1 KiB

    const int bk  = blockIdx.x;
    const int tid = threadIdx.x;
    const int k   = bk >> 2;
    const int ic  = bk & 3;

    // ---- stage: coalesced float4 loads (replaces R6's scattered gather) ----
    const float4* __restrict__ ogk = og + (size_t)k * PO;
    #pragma unroll
    for (int r = 0; r < PO / BLK; ++r) {
        const int j = r * BLK + tid;
        const float4 o = ogk[j];
        so[j] = (v4f){o.x, o.y, o.z, o.w};
    }
    qld[tid] = qg[(size_t)k * PS + ic * QPB + tid];
    __syncthreads();

    // ---- setup: lane owns 8 queries as 4 packed pairs (R6-identical) ----
    const int g  = tid >> 5;         // jgroup 0..7 (half-wave)
    const int gl = tid & 31;
    const int qb = gl * QL;

    v2f nsx[4], nsy[4], nsz[4], mint[4];
    #pragma unroll
    for (int p = 0; p < 4; ++p) {
        const float4 qa = qld[qb + 2 * p];
        const float4 qc = qld[qb + 2 * p + 1];
        nsx[p] = (v2f){-qa.x, -qc.x};
        nsy[p] = (v2f){-qa.y, -qc.y};
        nsz[p] = (v2f){-qa.z, -qc.z};
        mint[p] = (v2f){FLT_MAX, FLT_MAX};
    }

    // ---- hot loop: BYTE-IDENTICAL to R6 (proven 21.3 / absmax 0) ----
    const v4f* __restrict__ sog = &so[g * JPG];
    #pragma unroll 8
    for (int j = 0; j < JPG; ++j) {
        const v4f o = sog[j];
        const v2f oxy = __builtin_shufflevector(o, o, 0, 1);  // (x,y)
        const v2f ozw = __builtin_shufflevector(o, o, 2, 3);  // (z,w)
        #pragma unroll
        for (int p = 0; p < 4; ++p) {
            v2f t;
            asm("v_pk_fma_f32 %0, %1, %2, %3 op_sel:[0,0,1] op_sel_hi:[0,1,1]"
                : "=v"(t) : "v"(oxy), "v"(nsx[p]), "v"(ozw));
            asm("v_pk_fma_f32 %0, %1, %2, %0 op_sel:[1,0,0] op_sel_hi:[1,1,1]"
                : "+v"(t) : "v"(oxy), "v"(nsy[p]));
            asm("v_pk_fma_f32 %0, %1, %2, %0 op_sel:[0,0,0] op_sel_hi:[0,1,1]"
                : "+v"(t) : "v"(ozw), "v"(nsz[p]));
            mint[p].x = fminf(mint[p].x, t.x);
            mint[p].y = fminf(mint[p].y, t.y);
        }
    }

    // ---- cross-jgroup min via LDS (R6-identical) ----
    #pragma unroll
    for (int p = 0; p < 4; ++p) {
        red[g][qb + 2 * p]     = mint[p].x;
        red[g][qb + 2 * p + 1] = mint[p].y;
    }
    __syncthreads();

    float mq = red[0][tid];
    #pragma unroll
    for (int g2 = 1; g2 < NG; ++g2) mq = fminf(mq, red[g2][tid]);
    const float s2q = qld[tid].w;
    const float d   = sqrtf(fmaxf(fmaf(2.0f, mq, s2q), 0.0f));

    rsum[tid] = d;
    __syncthreads();
    for (int s = BLK / 2; s > 0; s >>= 1) {
        if (tid < s) rsum[tid] += rsum[tid + s];
        __syncthreads();
    }
    if (tid == 0) partial[bk] = rsum[0];
}

// ---------------- node 3: final 256 -> 1 reduce (one wave) ----------------

__global__ __launch_bounds__(64)
void cl_final(const float* __restrict__ partial, float* __restrict__ out)
{
    const int t = threadIdx.x;
    const float4 a = ((const float4*)partial)[t];   // 64 lanes x 4 = 256
    float v = (a.x + a.y) + (a.z + a.w);
    #pragma unroll
    for (int off = 32; off > 0; off >>= 1)
        v += __shfl_down(v, off, 64);
    if (t == 0) out[0] = v * (1.0f / (float)(K * PS));
}

// ---------------- fallback (tiny ws): R6's proven 2-node path ----------------

__global__ __launch_bounds__(BLK)
void cl_onepass_direct(const float* __restrict__ smplx_v,
                       const float* __restrict__ object_v,
                       const int*   __restrict__ spi,
                       const int*   __restrict__ opi,
                       const int*   __restrict__ bidx,
                       float*       __restrict__ partial)
{
    __shared__ v4f    so[PO];
    __shared__ float4 qld[QPB];
    __shared__ float  red[NG][QPB];
    __shared__ float  rsum[BLK];

    const int bk  = blockIdx.x;
    const int tid = threadIdx.x;
    const int k   = bk >> 2;
    const int ic  = bk & 3;
    const int b   = bidx[k];

    const float* __restrict__ ov = object_v + (size_t)b * VO * 3;
    #pragma unroll
    for (int r = 0; r < PO / BLK; ++r) {
        const int j  = r * BLK + tid;
        const int oj = opi[k * PO + j];
        const float x = ov[oj * 3 + 0];
        const float y = ov[oj * 3 + 1];
        const float z = ov[oj * 3 + 2];
        so[j] = (v4f){x, y, z, 0.5f * (x * x + y * y + z * z)};
    }
    {
        const int i  = ic * QPB + tid;
        const int si = spi[k * PS + i];
        const float* __restrict__ sv = smplx_v + ((size_t)b * VS + si) * 3;
        const float x = sv[0], y = sv[1], z = sv[2];
        qld[tid] = make_float4(x, y, z, x * x + y * y + z * z);
    }
    __syncthreads();

    const int g  = tid >> 5;
    const int gl = tid & 31;
    const int qb = gl * QL;

    v2f nsx[4], nsy[4], nsz[4], mint[4];
    #pragma unroll
    for (int p = 0; p < 4; ++p) {
        const float4 qa = qld[qb + 2 * p];
        const float4 qc = qld[qb + 2 * p + 1];
        nsx[p] = (v2f){-qa.x, -qc.x};
        nsy[p] = (v2f){-qa.y, -qc.y};
        nsz[p] = (v2f){-qa.z, -qc.z};
        mint[p] = (v2f){FLT_MAX, FLT_MAX};
    }

    const v4f* __restrict__ sog = &so[g * JPG];
    #pragma unroll 8
    for (int j = 0; j < JPG; ++j) {
        const v4f o = sog[j];
        const v2f oxy = __builtin_shufflevector(o, o, 0, 1);
        const v2f ozw = __builtin_shufflevector(o, o, 2, 3);
        #pragma unroll
        for (int p = 0; p < 4; ++p) {
            v2f t;
            asm("v_pk_fma_f32 %0, %1, %2, %3 op_sel:[0,0,1] op_sel_hi:[0,1,1]"
                : "=v"(t) : "v"(oxy), "v"(nsx[p]), "v"(ozw));
            asm("v_pk_fma_f32 %0, %1, %2, %0 op_sel:[1,0,0] op_sel_hi:[1,1,1]"
                : "+v"(t) : "v"(oxy), "v"(nsy[p]));
            asm("v_pk_fma_f32 %0, %1, %2, %0 op_sel:[0,0,0] op_sel_hi:[0,1,1]"
                : "+v"(t) : "v"(ozw), "v"(nsz[p]));
            mint[p].x = fminf(mint[p].x, t.x);
            mint[p].y = fminf(mint[p].y, t.y);
        }
    }

    #pragma unroll
    for (int p = 0; p < 4; ++p) {
        red[g][qb + 2 * p]     = mint[p].x;
        red[g][qb + 2 * p + 1] = mint[p].y;
    }
    __syncthreads();

    float mq = red[0][tid];
    #pragma unroll
    for (int g2 = 1; g2 < NG; ++g2) mq = fminf(mq, red[g2][tid]);
    const float s2q = qld[tid].w;
    const float d   = sqrtf(fmaxf(fmaf(2.0f, mq, s2q), 0.0f));

    rsum[tid] = d;
    __syncthreads();
    for (int s = BLK / 2; s > 0; s >>= 1) {
        if (tid < s) rsum[tid] += rsum[tid + s];
        __syncthreads();
    }
    if (tid == 0) partial[bk] = rsum[0];
}

// ---------------- launcher ----------------

extern "C" void kernel_launch(void* const* d_in, const int* in_sizes, int n_in,
                              void* d_out, int out_size, void* d_ws, size_t ws_size,
                              hipStream_t stream)
{
    const float* smplx_v       = (const float*)d_in[0];
    const float* object_v      = (const float*)d_in[1];
    const int*   smpl_part_idx = (const int*)d_in[2];
    const int*   obj_part_idx  = (const int*)d_in[3];
    const int*   batch_idx     = (const int*)d_in[4];
    float*       out           = (float*)d_out;

    // ws: og [K*PO float4] | qg [K*PS float4] | partial [GRID floats]
    const size_t og_elems = (size_t)K * PO;
    const size_t qg_elems = (size_t)K * PS;
    const size_t need = (og_elems + qg_elems) * sizeof(float4)
                      + GRID * sizeof(float);

    if (ws_size >= need) {
        float4* og      = (float4*)d_ws;
        float4* qg      = og + og_elems;
        float*  partial = (float*)(qg + qg_elems);

        cl_gather<<<PREP_GRID, 256, 0, stream>>>(
            smplx_v, object_v, smpl_part_idx, obj_part_idx, batch_idx, og, qg);
        cl_onepass<<<GRID, BLK, 0, stream>>>(og, qg, partial);
        cl_final<<<1, 64, 0, stream>>>(partial, out);
    } else {
        float* partial = (float*)d_ws;   // GRID floats
        cl_onepass_direct<<<GRID, BLK, 0, stream>>>(
            smplx_v, object_v, smpl_part_idx, obj_part_idx, batch_idx, partial);
        cl_final<<<1, 64, 0, stream>>>(partial, out);
    }
}

// Round 13
// 22.915 us; speedup vs baseline: 1.1087x; 1.1087x over previous
//
#include <hip/hip_runtime.h>
#include <float.h>
#include <math.h>

// Problem constants (from reference)
constexpr int B  = 16;
constexpr int VS = 10475;
constexpr int VO = 8192;
constexpr int K  = 64;
constexpr int PS = 1024;
constexpr int PO = 2048;

// Geometry: R6-proven skeleton (21.3 us): 256 blocks (1/CU) x 256 threads,
// block = (k, 256-query chunk), all 2048 objects staged in LDS, 8 half-wave
// jgroups x 256 objects, 8 queries/lane as 4 packed f32 pairs.
// R13 single change: hot loop is explicitly software-pipelined 4 deep --
// next 4 ds_read_b128 issued BEFORE computing the current 4, via register
// rotation, so LDS latency hides under the 4x20 VALU ops per stage.
constexpr int BLK  = 256;
constexpr int QPB  = 256;              // queries per block
constexpr int GRID = K * (PS / QPB);   // 256
constexpr int NG   = 8;                // jgroups (half-waves) per block
constexpr int JPG  = PO / NG;          // 256 objects per jgroup
constexpr int QL   = 8;                // queries per lane (4 packed pairs)

typedef float v2f __attribute__((ext_vector_type(2)));
typedef float v4f __attribute__((ext_vector_type(4)));

// ---------------- kernel 1: full min + block partial sum ----------------

__global__ __launch_bounds__(BLK)
void cl_onepass(const float* __restrict__ smplx_v,
                const float* __restrict__ object_v,
                const int*   __restrict__ spi,
                const int*   __restrict__ opi,
                const int*   __restrict__ bidx,
                float*       __restrict__ partial)   // [GRID]
{
    __shared__ v4f    so[PO];        // (x,y,z, 0.5*|o|^2) -> 32 KiB
    __shared__ float4 qld[QPB];      // (x,y,z, |s|^2)     ->  4 KiB
    __shared__ float  red[NG][QPB];  //                    ->  8 KiB
    __shared__ float  rsum[BLK];     //                    ->  1 KiB

    const int bk  = blockIdx.x;
    const int tid = threadIdx.x;
    const int k   = bk >> 2;
    const int ic  = bk & 3;
    const int b   = bidx[k];

    // ---- gather: all 2048 objects of this k into LDS (R6-identical) ----
    const float* __restrict__ ov = object_v + (size_t)b * VO * 3;
    #pragma unroll
    for (int r = 0; r < PO / BLK; ++r) {
        const int j  = r * BLK + tid;
        const int oj = opi[k * PO + j];
        const float x = ov[oj * 3 + 0];
        const float y = ov[oj * 3 + 1];
        const float z = ov[oj * 3 + 2];
        so[j] = (v4f){x, y, z, 0.5f * (x * x + y * y + z * z)};
    }
    // ---- gather: this block's 256 queries (R6-identical) ----
    {
        const int i  = ic * QPB + tid;
        const int si = spi[k * PS + i];
        const float* __restrict__ sv = smplx_v + ((size_t)b * VS + si) * 3;
        const float x = sv[0], y = sv[1], z = sv[2];
        qld[tid] = make_float4(x, y, z, x * x + y * y + z * z);
    }
    __syncthreads();

    // ---- setup: lane owns 8 queries as 4 packed pairs (R6-identical) ----
    const int g  = tid >> 5;         // jgroup 0..7 (half-wave)
    const int gl = tid & 31;
    const int qb = gl * QL;

    v2f nsx[4], nsy[4], nsz[4], mint[4];
    #pragma unroll
    for (int p = 0; p < 4; ++p) {
        const float4 qa = qld[qb + 2 * p];
        const float4 qc = qld[qb + 2 * p + 1];
        nsx[p] = (v2f){-qa.x, -qc.x};
        nsy[p] = (v2f){-qa.y, -qc.y};
        nsz[p] = (v2f){-qa.z, -qc.z};
        mint[p] = (v2f){FLT_MAX, FLT_MAX};
    }

    // ---- hot loop: R6 asm body, explicitly software-pipelined 4 deep ----
    // t = 0.5*|o|^2 - s.o for 2 queries per v_pk_fma_f32; op_sel splats the
    // object components straight out of the (x,y),(z,w) register pairs.
    const v4f* __restrict__ sog = &so[g * JPG];

    #define CL_COMP(OREG)                                                     \
    {                                                                         \
        const v2f oxy = __builtin_shufflevector((OREG), (OREG), 0, 1);        \
        const v2f ozw = __builtin_shufflevector((OREG), (OREG), 2, 3);        \
        _Pragma("unroll")                                                     \
        for (int p = 0; p < 4; ++p) {                                         \
            v2f t;                                                            \
            asm("v_pk_fma_f32 %0, %1, %2, %3 op_sel:[0,0,1] op_sel_hi:[0,1,1]"\
                : "=v"(t) : "v"(oxy), "v"(nsx[p]), "v"(ozw));                 \
            asm("v_pk_fma_f32 %0, %1, %2, %0 op_sel:[1,0,0] op_sel_hi:[1,1,1]"\
                : "+v"(t) : "v"(oxy), "v"(nsy[p]));                           \
            asm("v_pk_fma_f32 %0, %1, %2, %0 op_sel:[0,0,0] op_sel_hi:[0,1,1]"\
                : "+v"(t) : "v"(ozw), "v"(nsz[p]));                           \
            mint[p].x = fminf(mint[p].x, t.x);                                \
            mint[p].y = fminf(mint[p].y, t.y);                                \
        }                                                                     \
    }

    v4f c0 = sog[0], c1 = sog[1], c2 = sog[2], c3 = sog[3];
    for (int j = 0; j < JPG - 4; j += 4) {
        const v4f n0 = sog[j + 4];
        const v4f n1 = sog[j + 5];
        const v4f n2 = sog[j + 6];
        const v4f n3 = sog[j + 7];
        CL_COMP(c0); CL_COMP(c1); CL_COMP(c2); CL_COMP(c3);
        c0 = n0; c1 = n1; c2 = n2; c3 = n3;
    }
    CL_COMP(c0); CL_COMP(c1); CL_COMP(c2); CL_COMP(c3);
    #undef CL_COMP

    // ---- cross-jgroup min via LDS (R6-identical) ----
    #pragma unroll
    for (int p = 0; p < 4; ++p) {
        red[g][qb + 2 * p]     = mint[p].x;
        red[g][qb + 2 * p + 1] = mint[p].y;
    }
    __syncthreads();

    // thread t finalizes query t of this block
    float mq = red[0][tid];
    #pragma unroll
    for (int g2 = 1; g2 < NG; ++g2) mq = fminf(mq, red[g2][tid]);
    const float s2q = qld[tid].w;
    const float d   = sqrtf(fmaxf(fmaf(2.0f, mq, s2q), 0.0f));

    // ---- deterministic block tree-sum (R6-identical) ----
    rsum[tid] = d;
    __syncthreads();
    for (int s = BLK / 2; s > 0; s >>= 1) {
        if (tid < s) rsum[tid] += rsum[tid + s];
        __syncthreads();
    }
    if (tid == 0) partial[bk] = rsum[0];
}

// ---------------- kernel 2: final 256 -> 1 reduce (one wave) ----------------

__global__ __launch_bounds__(64)
void cl_final(const float* __restrict__ partial, float* __restrict__ out)
{
    const int t = threadIdx.x;
    const float4 a = ((const float4*)partial)[t];   // 64 lanes x 4 = 256
    float v = (a.x + a.y) + (a.z + a.w);
    #pragma unroll
    for (int off = 32; off > 0; off >>= 1)
        v += __shfl_down(v, off, 64);
    if (t == 0) out[0] = v * (1.0f / (float)(K * PS));
}

// ---------------- launcher ----------------

extern "C" void kernel_launch(void* const* d_in, const int* in_sizes, int n_in,
                              void* d_out, int out_size, void* d_ws, size_t ws_size,
                              hipStream_t stream)
{
    const float* smplx_v       = (const float*)d_in[0];
    const float* object_v      = (const float*)d_in[1];
    const int*   smpl_part_idx = (const int*)d_in[2];
    const int*   obj_part_idx  = (const int*)d_in[3];
    const int*   batch_idx     = (const int*)d_in[4];
    float*       out           = (float*)d_out;

    float* partial = (float*)d_ws;   // GRID floats

    cl_onepass<<<GRID, BLK, 0, stream>>>(
        smplx_v, object_v, smpl_part_idx, obj_part_idx, batch_idx, partial);
    cl_final<<<1, 64, 0, stream>>>(partial, out);
}

// Round 14
// 19.417 us; speedup vs baseline: 1.3084x; 1.1801x over previous
//
#include <hip/hip_runtime.h>
#include <float.h>
#include <math.h>

// Problem constants (from reference)
constexpr int B  = 16;
constexpr int VS = 10475;
constexpr int VO = 8192;
constexpr int K  = 64;
constexpr int PS = 1024;
constexpr int PO = 2048;

// R14: R6 skeleton with 4x the waves and NO gather duplication.
// 256 blocks (1/CU) x 1024 threads = 16 waves/CU (4/SIMD) -- the one
// config that adds latency-hiding TLP without duplicating the scattered
// gather (R9 doubled gather; R7 bundled the min3 regression).
// Block = (k, 256-query chunk); all 2048 objects staged once in LDS;
// 16 FULL-WAVE jgroups x 128 objects; each lane owns 4 queries (2 pairs).
constexpr int BLK  = 1024;
constexpr int QPB  = 256;              // queries per block
constexpr int GRID = K * (PS / QPB);   // 256
constexpr int NG   = 16;               // jgroups = waves per block
constexpr int JPG  = PO / NG;          // 128 objects per jgroup
constexpr int QL   = 4;                // queries per lane (2 packed pairs)

typedef float v2f __attribute__((ext_vector_type(2)));
typedef float v4f __attribute__((ext_vector_type(4)));

// ---------------- kernel 1: full min + block partial sum ----------------

__global__ __launch_bounds__(BLK)
void cl_onepass(const float* __restrict__ smplx_v,
                const float* __restrict__ object_v,
                const int*   __restrict__ spi,
                const int*   __restrict__ opi,
                const int*   __restrict__ bidx,
                float*       __restrict__ partial)   // [GRID]
{
    __shared__ v4f    so[PO];        // (x,y,z, 0.5*|o|^2) -> 32 KiB
    __shared__ float4 qld[QPB];      // (x,y,z, |s|^2)     ->  4 KiB
    __shared__ float  red[NG][QPB];  //                    -> 16 KiB
    __shared__ float  wsum[NG];      //                    -> 64 B

    const int bk  = blockIdx.x;
    const int tid = threadIdx.x;
    const int k   = bk >> 2;
    const int ic  = bk & 3;
    const int b   = bidx[k];

    // ---- gather: all 2048 objects, 2 per thread (16 waves overlap) ----
    const float* __restrict__ ov = object_v + (size_t)b * VO * 3;
    #pragma unroll
    for (int r = 0; r < PO / BLK; ++r) {
        const int j  = r * BLK + tid;
        const int oj = opi[k * PO + j];
        const float x = ov[oj * 3 + 0];
        const float y = ov[oj * 3 + 1];
        const float z = ov[oj * 3 + 2];
        so[j] = (v4f){x, y, z, 0.5f * (x * x + y * y + z * z)};
    }
    // ---- gather: this block's 256 queries (waves 0-3) ----
    if (tid < QPB) {
        const int i  = ic * QPB + tid;
        const int si = spi[k * PS + i];
        const float* __restrict__ sv = smplx_v + ((size_t)b * VS + si) * 3;
        const float x = sv[0], y = sv[1], z = sv[2];
        qld[tid] = make_float4(x, y, z, x * x + y * y + z * z);
    }
    __syncthreads();

    // ---- setup: lane owns 4 queries as 2 packed pairs ----
    const int g    = tid >> 6;       // jgroup == wave id (0..15)
    const int lane = tid & 63;
    const int qb   = lane * QL;

    v2f nsx[2], nsy[2], nsz[2], mint[2];
    #pragma unroll
    for (int p = 0; p < 2; ++p) {
        const float4 qa = qld[qb + 2 * p];
        const float4 qc = qld[qb + 2 * p + 1];
        nsx[p] = (v2f){-qa.x, -qc.x};
        nsy[p] = (v2f){-qa.y, -qc.y};
        nsz[p] = (v2f){-qa.z, -qc.z};
        mint[p] = (v2f){FLT_MAX, FLT_MAX};
    }

    // ---- hot loop (R6-proven asm): this wave's 128 objects, broadcast ----
    // t = 0.5*|o|^2 - s.o for 2 queries per v_pk_fma_f32; op_sel splats the
    // object components straight out of the (x,y),(z,w) register pairs.
    const v4f* __restrict__ sog = &so[g * JPG];
    #pragma unroll 8
    for (int j = 0; j < JPG; ++j) {
        const v4f o = sog[j];
        const v2f oxy = __builtin_shufflevector(o, o, 0, 1);  // (x,y)
        const v2f ozw = __builtin_shufflevector(o, o, 2, 3);  // (z,w)
        #pragma unroll
        for (int p = 0; p < 2; ++p) {
            v2f t;
            asm("v_pk_fma_f32 %0, %1, %2, %3 op_sel:[0,0,1] op_sel_hi:[0,1,1]"
                : "=v"(t) : "v"(oxy), "v"(nsx[p]), "v"(ozw));
            asm("v_pk_fma_f32 %0, %1, %2, %0 op_sel:[1,0,0] op_sel_hi:[1,1,1]"
                : "+v"(t) : "v"(oxy), "v"(nsy[p]));
            asm("v_pk_fma_f32 %0, %1, %2, %0 op_sel:[0,0,0] op_sel_hi:[0,1,1]"
                : "+v"(t) : "v"(ozw), "v"(nsz[p]));
            mint[p].x = fminf(mint[p].x, t.x);
            mint[p].y = fminf(mint[p].y, t.y);
        }
    }

    // ---- cross-jgroup min via LDS ----
    #pragma unroll
    for (int p = 0; p < 2; ++p) {
        red[g][qb + 2 * p]     = mint[p].x;
        red[g][qb + 2 * p + 1] = mint[p].y;
    }
    __syncthreads();

    // ---- finalize query tid (waves 0-3); cheap 2-level wave reduce ----
    float d = 0.0f;
    if (tid < QPB) {
        float mq = red[0][tid];
        #pragma unroll
        for (int g2 = 1; g2 < NG; ++g2) mq = fminf(mq, red[g2][tid]);
        const float s2q = qld[tid].w;
        d = sqrtf(fmaxf(fmaf(2.0f, mq, s2q), 0.0f));
    }
    #pragma unroll
    for (int off = 32; off > 0; off >>= 1)
        d += __shfl_down(d, off, 64);
    if (lane == 0) wsum[g] = d;     // waves 4-15 contribute 0
    __syncthreads();
    if (tid < 64) {
        float v = (tid < NG) ? wsum[tid] : 0.0f;
        #pragma unroll
        for (int off = 8; off > 0; off >>= 1)
            v += __shfl_down(v, off, 64);
        if (tid == 0) partial[bk] = v;
    }
}

// ---------------- kernel 2: final 256 -> 1 reduce (one wave) ----------------

__global__ __launch_bounds__(64)
void cl_final(const float* __restrict__ partial, float* __restrict__ out)
{
    const int t = threadIdx.x;
    const float4 a = ((const float4*)partial)[t];   // 64 lanes x 4 = 256
    float v = (a.x + a.y) + (a.z + a.w);
    #pragma unroll
    for (int off = 32; off > 0; off >>= 1)
        v += __shfl_down(v, off, 64);
    if (t == 0) out[0] = v * (1.0f / (float)(K * PS));
}

// ---------------- launcher ----------------

extern "C" void kernel_launch(void* const* d_in, const int* in_sizes, int n_in,
                              void* d_out, int out_size, void* d_ws, size_t ws_size,
                              hipStream_t stream)
{
    const float* smplx_v       = (const float*)d_in[0];
    const float* object_v      = (const float*)d_in[1];
    const int*   smpl_part_idx = (const int*)d_in[2];
    const int*   obj_part_idx  = (const int*)d_in[3];
    const int*   batch_idx     = (const int*)d_in[4];
    float*       out           = (float*)d_out;

    float* partial = (float*)d_ws;   // GRID floats

    cl_onepass<<<GRID, BLK, 0, stream>>>(
        smplx_v, object_v, smpl_part_idx, obj_part_idx, batch_idx, partial);
    cl_final<<<1, 64, 0, stream>>>(partial, out);
}